// Round 4
// baseline (161.131 us; speedup 1.0000x reference)
//
#include <hip/hip_runtime.h>

#define IMG 512
#define CS 36                     // shorts per Ht column: 2 ring slots (32) + 4 pad
#define CH_STRIDE (16 * CS)       // 576 shorts: one channel (16 cols) of one wave
#define WV_STRIDE (5 * CH_STRIDE) // 2880 shorts: one wave's 5 channels

typedef short short8  __attribute__((ext_vector_type(8)));
typedef float floatx4 __attribute__((ext_vector_type(4)));
typedef int   intx2   __attribute__((ext_vector_type(2)));

// 1D Gaussian (sigma=1.5, K=11) — identical values to prior rounds.
__device__ static constexpr float W11F[11] = {
    0.00102838f, 0.00759876f, 0.03600077f, 0.10936069f, 0.21300554f,
    0.26601173f,
    0.21300554f, 0.10936069f, 0.03600077f, 0.00759876f, 0.00102838f};

// pack two fp32 -> two bf16 (round-half-up; finite positive values)
__device__ __forceinline__ unsigned pack2bf16(float a, float b) {
    const unsigned ua = __float_as_uint(a) + 0x8000u;
    const unsigned ub = __float_as_uint(b) + 0x8000u;
    return __builtin_amdgcn_perm(ub, ua, 0x07060302u);
}

__device__ __forceinline__ void ht_store(ushort* p, floatx4 c) {
    intx2 d;
    d.x = (int)pack2bf16(c[0], c[1]);
    d.y = (int)pack2bf16(c[2], c[3]);
    *(intx2*)p = d;               // 8-B aligned by construction
}

__device__ __forceinline__ short8 ht_load(const ushort* p) {
    union { intx2 d[2]; short8 s; } u;
    u.d[0] = *(const intx2*)p;
    u.d[1] = *(const intx2*)(p + 4);
    return u.s;
}

// Persistent column-strip blocks. Block = 4 waves (256 thr), 64 out-cols,
// 256 out-rows (half the image column). Wave = 16 out-cols x 256 out-rows:
// 17 staged 16-row tiles ROLL through the 2-slot LDS ring + 2 register
// buffer sets, producing 16 output windows back-to-back. Pipeline fill is
// paid once per 16 windows (was once per 4), block count 3072 -> 768
// (exactly 3/CU), y-halo overfetch 25% -> 6%. No inner barriers: each
// wave's ring region is private.
__global__ __launch_bounds__(256, 4) void ssim_mfma_roll(
        const float* __restrict__ pred, const float* __restrict__ gt,
        float* __restrict__ partials)
{
    __shared__ ushort Ht[4 * WV_STRIDE];   // 23,040 B
    __shared__ ushort wlut[16];
    __shared__ float wsum[4];

    const int tid  = threadIdx.x;
    const int wv   = tid >> 6;
    const int lane = tid & 63;
    const int n    = lane & 15;
    const int quad = lane >> 4;

    if (tid < 16) {
        const float w = (tid < 11) ? W11F[tid] : 0.f;
        wlut[tid] = (ushort)((__float_as_uint(w) + 0x8000u) >> 16);
    }
    __syncthreads();

    // band fragment: w[(quad*8+j) - n - 3]; B in H-pass, A in V-pass.
    short8 band;
#pragma unroll
    for (int j = 0; j < 8; ++j) {
        const int t = quad * 8 + j - n - 3;
        band[j] = (short)wlut[((unsigned)t < 11u) ? t : 15];
    }

    const int bx = blockIdx.x, yh = blockIdx.y, plane = blockIdx.z;
    const long pb = (long)plane * (IMG * IMG);
    const float* pplane = pred + pb;
    const float* gplane = gt + pb;
    const int xs  = bx * 64 + wv * 16 - 8;  // 32-col input window start
    const int y0  = yh * 256;               // 256-row output strip
    ushort* ht    = &Ht[wv * WV_STRIDE];
    const bool cols_ok = (xs >= 0) && (xs + 32 <= IMG);

// stage tile t (16 input rows starting at y0-8+16t) into named buffers
#define LOADT(t, pf, gf)                                                     \
    {                                                                        \
        const int ys  = y0 - 8 + (t) * 16;                                   \
        const int row = ys + n;                                              \
        const int c0  = xs + quad * 8;                                       \
        if (cols_ok && ys >= 0 && ys + 16 <= IMG) {                          \
            const float* pr = pplane + (long)row * IMG + c0;                 \
            const float* gr = gplane + (long)row * IMG + c0;                 \
            *(float4*)&pf[0] = *(const float4*)pr;                           \
            *(float4*)&pf[4] = *(const float4*)(pr + 4);                     \
            *(float4*)&gf[0] = *(const float4*)gr;                           \
            *(float4*)&gf[4] = *(const float4*)(gr + 4);                     \
        } else {                                                             \
            const bool rv = (unsigned)row < (unsigned)IMG;                   \
            const int rowc = rv ? row : 0;                                   \
            const float* pr = pplane + (long)rowc * IMG;                     \
            const float* gr = gplane + (long)rowc * IMG;                     \
            _Pragma("unroll")                                                \
            for (int j = 0; j < 8; ++j) {                                    \
                const int cc = c0 + j;                                       \
                const bool ok = rv && ((unsigned)cc < (unsigned)IMG);        \
                const int ccc = ok ? cc : 0;                                 \
                const float pv = pr[ccc], gv = gr[ccc];                      \
                pf[j] = ok ? pv : 0.f;                                       \
                gf[j] = ok ? gv : 0.f;                                       \
            }                                                                \
        }                                                                    \
    }

// H-conv tile t via 5 MFMAs, store into ring slot t&1 (k = slot*16 + m)
#define COMPT(t, pf, gf)                                                     \
    {                                                                        \
        union { unsigned u[4]; short8 s; } ap, ag, app, agg, apg;            \
        _Pragma("unroll")                                                    \
        for (int h = 0; h < 4; ++h) {                                        \
            const float p0 = pf[2*h], p1 = pf[2*h+1];                        \
            const float g0 = gf[2*h], g1 = gf[2*h+1];                        \
            ap.u [h] = pack2bf16(p0, p1);                                    \
            ag.u [h] = pack2bf16(g0, g1);                                    \
            app.u[h] = pack2bf16(p0 * p0, p1 * p1);                          \
            agg.u[h] = pack2bf16(g0 * g0, g1 * g1);                          \
            apg.u[h] = pack2bf16(p0 * g0, p1 * g1);                          \
        }                                                                    \
        const floatx4 z = {0.f, 0.f, 0.f, 0.f};                              \
        const floatx4 cp  = __builtin_amdgcn_mfma_f32_16x16x32_bf16(ap.s,  band, z, 0, 0, 0); \
        const floatx4 cg  = __builtin_amdgcn_mfma_f32_16x16x32_bf16(ag.s,  band, z, 0, 0, 0); \
        const floatx4 cpp = __builtin_amdgcn_mfma_f32_16x16x32_bf16(app.s, band, z, 0, 0, 0); \
        const floatx4 cgg = __builtin_amdgcn_mfma_f32_16x16x32_bf16(agg.s, band, z, 0, 0, 0); \
        const floatx4 cpg = __builtin_amdgcn_mfma_f32_16x16x32_bf16(apg.s, band, z, 0, 0, 0); \
        const int wb = n * CS + ((t) & 1) * 16 + quad * 4;                   \
        ht_store(&ht[0 * CH_STRIDE + wb], cp);                               \
        ht_store(&ht[1 * CH_STRIDE + wb], cg);                               \
        ht_store(&ht[2 * CH_STRIDE + wb], cpp);                              \
        ht_store(&ht[3 * CH_STRIDE + wb], cgg);                              \
        ht_store(&ht[4 * CH_STRIDE + wb], cpg);                              \
    }

// V window: lower 16 k-rows from ring slot SLO, upper from slot SHI
#define VPASS(SLO, SHI)                                                      \
    {                                                                        \
        const int koff = ((quad < 2) ? (SLO) : (SHI)) * 16 + (quad & 1) * 8; \
        const int rb   = n * CS + koff;                                      \
        const short8 bp  = ht_load(&ht[0 * CH_STRIDE + rb]);                 \
        const short8 bg  = ht_load(&ht[1 * CH_STRIDE + rb]);                 \
        const short8 bpp = ht_load(&ht[2 * CH_STRIDE + rb]);                 \
        const short8 bgg = ht_load(&ht[3 * CH_STRIDE + rb]);                 \
        const short8 bpg = ht_load(&ht[4 * CH_STRIDE + rb]);                 \
        const floatx4 z = {0.f, 0.f, 0.f, 0.f};                              \
        const floatx4 mp  = __builtin_amdgcn_mfma_f32_16x16x32_bf16(band, bp,  z, 0, 0, 0); \
        const floatx4 mg  = __builtin_amdgcn_mfma_f32_16x16x32_bf16(band, bg,  z, 0, 0, 0); \
        const floatx4 mpp = __builtin_amdgcn_mfma_f32_16x16x32_bf16(band, bpp, z, 0, 0, 0); \
        const floatx4 mgg = __builtin_amdgcn_mfma_f32_16x16x32_bf16(band, bgg, z, 0, 0, 0); \
        const floatx4 mpg = __builtin_amdgcn_mfma_f32_16x16x32_bf16(band, bpg, z, 0, 0, 0); \
        _Pragma("unroll")                                                    \
        for (int r = 0; r < 4; ++r) {                                        \
            const float mu1 = mp[r], mu2 = mg[r];                            \
            const float mu1sq = mu1 * mu1, mu2sq = mu2 * mu2;                \
            const float mu12 = mu1 * mu2;                                    \
            const float s1  = mpp[r] - mu1sq;                                \
            const float s2  = mgg[r] - mu2sq;                                \
            const float s12 = mpg[r] - mu12;                                 \
            const float num = (2.f * mu12 + C1) * (2.f * s12 + C2);          \
            const float den = (mu1sq + mu2sq + C1) * (s1 + s2 + C2);         \
            lsum += num * __builtin_amdgcn_rcpf(den);                        \
        }                                                                    \
    }

    const float C1 = 1e-4f, C2 = 9e-4f;
    float lsum = 0.f;

    // 2 register buffer sets, rolled: buffer parity == tile parity
    float pA[8], gA[8], pB[8], gB[8];

    // ---- pipeline fill ----
    LOADT(0, pA, gA)
    LOADT(1, pB, gB)
    COMPT(0, pA, gA)          // slot 0
    LOADT(2, pA, gA)
    COMPT(1, pB, gB)          // slot 1
    VPASS(0, 1)               // window 0: tiles 0,1

    // ---- steady state: 2 tiles / 2 windows per iteration ----
    for (int t = 2; t <= 14; t += 2) {
        LOADT(t + 1, pB, gB)
        COMPT(t, pA, gA)      // slot 0
        VPASS(1, 0)           // window t-1: tiles t-1,t
        LOADT(t + 2, pA, gA)
        COMPT(t + 1, pB, gB)  // slot 1
        VPASS(0, 1)           // window t: tiles t,t+1
    }

    // ---- drain: tiles 0..16 loaded, 0..15 computed, windows 0..14 done ----
    COMPT(16, pA, gA)         // slot 0
    VPASS(1, 0)               // window 15: tiles 15,16

    // ---- block reduction -> one partial per block ----
#pragma unroll
    for (int off = 32; off > 0; off >>= 1)
        lsum += __shfl_down(lsum, off);
    if (lane == 0) wsum[wv] = lsum;
    __syncthreads();
    if (tid == 0)
        partials[(plane * 2 + yh) * 8 + bx] =
            wsum[0] + wsum[1] + wsum[2] + wsum[3];
}

__global__ __launch_bounds__(1024) void ssim_finalize(
        const float* __restrict__ partials, float* __restrict__ out,
        int nparts, double inv_n)
{
    __shared__ double ws[16];
    double s = 0.0;
    for (int i = threadIdx.x; i < nparts; i += 1024)
        s += (double)partials[i];
#pragma unroll
    for (int off = 32; off > 0; off >>= 1)
        s += __shfl_down(s, off);
    if ((threadIdx.x & 63) == 0) ws[threadIdx.x >> 6] = s;
    __syncthreads();
    if (threadIdx.x == 0) {
        double t = 0.0;
#pragma unroll
        for (int i = 0; i < 16; ++i) t += ws[i];
        out[0] = (float)(1.0 - t * inv_n);
    }
}

extern "C" void kernel_launch(void* const* d_in, const int* in_sizes, int n_in,
                              void* d_out, int out_size, void* d_ws, size_t ws_size,
                              hipStream_t stream)
{
    const float* pred = (const float*)d_in[0];
    const float* gt   = (const float*)d_in[1];
    float* out        = (float*)d_out;
    float* partials   = (float*)d_ws;          // 8*2*48 = 768 floats

    const long n = (long)in_sizes[0];
    const int planes = (int)(n / (long)(IMG * IMG));   // B*C = 48

    dim3 grid(8, 2, planes);                   // 64-col x 256-row strips
    ssim_mfma_roll<<<grid, 256, 0, stream>>>(pred, gt, partials);
    ssim_finalize<<<1, 1024, 0, stream>>>(partials, out,
                                          8 * 2 * planes, 1.0 / (double)n);
}

// Round 7
// 159.757 us; speedup vs baseline: 1.0086x; 1.0086x over previous
//
#include <hip/hip_runtime.h>

#define IMG 512
#define CS 36                     // shorts per Ht column: 2 ring slots (32) + 4 pad
#define CH_STRIDE (16 * CS)       // 576 shorts: one channel (16 cols)
#define WV_STRIDE (5 * CH_STRIDE) // 2880 shorts: 5 channels (one wave)

typedef short short8  __attribute__((ext_vector_type(8)));
typedef float floatx4 __attribute__((ext_vector_type(4)));
typedef int   intx2   __attribute__((ext_vector_type(2)));

// 1D Gaussian (sigma=1.5, K=11) — identical values to prior rounds.
__device__ static constexpr float W11F[11] = {
    0.00102838f, 0.00759876f, 0.03600077f, 0.10936069f, 0.21300554f,
    0.26601173f,
    0.21300554f, 0.10936069f, 0.03600077f, 0.00759876f, 0.00102838f};

__device__ __forceinline__ unsigned pack2bf16(float a, float b) {
    const unsigned ua = __float_as_uint(a) + 0x8000u;
    const unsigned ub = __float_as_uint(b) + 0x8000u;
    return __builtin_amdgcn_perm(ub, ua, 0x07060302u);
}

__device__ __forceinline__ void ht_store(ushort* p, floatx4 c) {
    intx2 d;
    d.x = (int)pack2bf16(c[0], c[1]);
    d.y = (int)pack2bf16(c[2], c[3]);
    *(intx2*)p = d;               // 8-B aligned (CS*2 = 72B row stride)
}

__device__ __forceinline__ short8 ht_load(const ushort* p) {
    union { intx2 d[2]; short8 s; } u;
    u.d[0] = *(const intx2*)p;
    u.d[1] = *(const intx2*)(p + 4);
    return u.s;
}

// One wave per block (64 thr). Wave = 16 out-cols x 256 out-rows: 17 input
// tiles (16 rows x 32 cols) roll through the ring. Staging is per-wave LDS
// DMA: 4 x global_load_lds(16B) per tile = 1KB coalesced instructions (16
// fully-used lines each) replacing 16-row x 2KB-stride scattered loads (32
// half-used lines each) that thrashed L1 sets. 3 tile buffers + counted
// s_waitcnt vmcnt(8) (via builtin, gfx9 encoding) keep 2 tiles of DMA in
// flight across the whole loop (never drained to 0 mid-loop). Source-addr
// XOR pre-swizzle (chunk ^= row&7) makes fragment ds_read_b128s 2-way-
// bank-free. Edges: clamped DMA address + LDS zero-fixup after vmcnt-land.
// No barriers in the main loop (single-wave block). Steady-state loop is
// fully unrolled so buffer indices and ring slots are compile-time.
__global__ __launch_bounds__(64) void ssim_mfma_dma(
        const float* __restrict__ pred, const float* __restrict__ gt,
        float* __restrict__ partials)
{
    __shared__ __align__(16) ushort Ht[WV_STRIDE];  // 5,760 B
    __shared__ __align__(16) float  Sst[3][2][512]; // 12,288 B
    __shared__ ushort wlut[16];

    const int lane = threadIdx.x;
    const int n    = lane & 15;
    const int quad = lane >> 4;

    if (lane < 16) {
        const float w = (lane < 11) ? W11F[lane] : 0.f;
        wlut[lane] = (ushort)((__float_as_uint(w) + 0x8000u) >> 16);
    }
    __syncthreads();

    // band fragment: w[(quad*8+j) - n - 3]; B in H-pass, A in V-pass.
    short8 band;
#pragma unroll
    for (int j = 0; j < 8; ++j) {
        const int t = quad * 8 + j - n - 3;
        band[j] = (short)wlut[((unsigned)t < 11u) ? t : 15];
    }

    const int bx = blockIdx.x, yh = blockIdx.y, plane = blockIdx.z;
    const long pb = (long)plane * (IMG * IMG);
    const float* pplane = pred + pb;
    const float* gplane = gt + pb;
    const int xs = bx * 16 - 8;             // 32-col input window start
    const int y0 = yh * 256;                // 256-row output strip
    ushort* ht   = &Ht[0];

    // ---- staging lane constants (swizzled source addressing) ----
    const int lr   = lane >> 3;             // tile row within half (0..7)
    const int pos  = lane & 7;              // LDS chunk slot within row
    const int sch  = pos ^ (lr & 7);        // source chunk (XOR pre-swizzle)
    const int c0s  = xs + sch * 4;          // source col of that chunk
    const bool colOOB = (c0s < 0) || (c0s > IMG - 4);
    const int scol = colOOB ? 0 : c0s;

#define AS1 const __attribute__((address_space(1))) void*
#define AS3 __attribute__((address_space(3))) void*

// stage tile t (16 rows at y0-8+16t, 32 cols at xs) into buffer b: 4x 1KB DMA
#define STAGE(t, b)                                                          \
    {                                                                        \
        const int ys_ = y0 - 8 + (t) * 16;                                   \
        int ra = ys_ + lr;                                                   \
        int rb = ys_ + lr + 8;                                               \
        ra = ra < 0 ? 0 : (ra > IMG - 1 ? IMG - 1 : ra);                     \
        rb = rb < 0 ? 0 : (rb > IMG - 1 ? IMG - 1 : rb);                     \
        const float* pa_ = pplane + (long)ra * IMG + scol;                   \
        const float* pb_ = pplane + (long)rb * IMG + scol;                   \
        const float* ga_ = gplane + (long)ra * IMG + scol;                   \
        const float* gb_ = gplane + (long)rb * IMG + scol;                   \
        __builtin_amdgcn_global_load_lds((AS1)pa_, (AS3)&Sst[b][0][0],   16, 0, 0); \
        __builtin_amdgcn_global_load_lds((AS1)pb_, (AS3)&Sst[b][0][256], 16, 0, 0); \
        __builtin_amdgcn_global_load_lds((AS1)ga_, (AS3)&Sst[b][1][0],   16, 0, 0); \
        __builtin_amdgcn_global_load_lds((AS1)gb_, (AS3)&Sst[b][1][256], 16, 0, 0); \
    }

// zero OOB slots of tile t in buffer b (runs after its DMA has landed)
#define FIX(t, b)                                                            \
    {                                                                        \
        const int ys_ = y0 - 8 + (t) * 16;                                   \
        const int ra = ys_ + lr, rb = ra + 8;                                \
        const float4 f4z = {0.f, 0.f, 0.f, 0.f};                             \
        if (colOOB || ((unsigned)ra > (unsigned)(IMG - 1))) {                \
            *(float4*)&Sst[b][0][lane * 4] = f4z;                            \
            *(float4*)&Sst[b][1][lane * 4] = f4z;                            \
        }                                                                    \
        if (colOOB || ((unsigned)rb > (unsigned)(IMG - 1))) {                \
            *(float4*)&Sst[b][0][256 + lane * 4] = f4z;                      \
            *(float4*)&Sst[b][1][256 + lane * 4] = f4z;                      \
        }                                                                    \
    }

// H-conv tile t via 5 MFMAs, store into ring slot t&1
#define COMPT(t, pf, gf)                                                     \
    {                                                                        \
        union { unsigned u[4]; short8 s; } ap, ag, app, agg, apg;            \
        _Pragma("unroll")                                                    \
        for (int h = 0; h < 4; ++h) {                                        \
            const float p0 = pf[2*h], p1 = pf[2*h+1];                        \
            const float g0 = gf[2*h], g1 = gf[2*h+1];                        \
            ap.u [h] = pack2bf16(p0, p1);                                    \
            ag.u [h] = pack2bf16(g0, g1);                                    \
            app.u[h] = pack2bf16(p0 * p0, p1 * p1);                          \
            agg.u[h] = pack2bf16(g0 * g0, g1 * g1);                          \
            apg.u[h] = pack2bf16(p0 * g0, p1 * g1);                          \
        }                                                                    \
        const floatx4 z = {0.f, 0.f, 0.f, 0.f};                              \
        const floatx4 cp  = __builtin_amdgcn_mfma_f32_16x16x32_bf16(ap.s,  band, z, 0, 0, 0); \
        const floatx4 cg  = __builtin_amdgcn_mfma_f32_16x16x32_bf16(ag.s,  band, z, 0, 0, 0); \
        const floatx4 cpp = __builtin_amdgcn_mfma_f32_16x16x32_bf16(app.s, band, z, 0, 0, 0); \
        const floatx4 cgg = __builtin_amdgcn_mfma_f32_16x16x32_bf16(agg.s, band, z, 0, 0, 0); \
        const floatx4 cpg = __builtin_amdgcn_mfma_f32_16x16x32_bf16(apg.s, band, z, 0, 0, 0); \
        const int wb = n * CS + ((t) & 1) * 16 + quad * 4;                   \
        ht_store(&ht[0 * CH_STRIDE + wb], cp);                               \
        ht_store(&ht[1 * CH_STRIDE + wb], cg);                               \
        ht_store(&ht[2 * CH_STRIDE + wb], cpp);                              \
        ht_store(&ht[3 * CH_STRIDE + wb], cgg);                              \
        ht_store(&ht[4 * CH_STRIDE + wb], cpg);                              \
    }

// H-pass sourcing A-fragments from swizzled staging buffer b
#define COMPL(t, b)                                                          \
    {                                                                        \
        const int sw8_ = n & 7;                                              \
        const int o0 = n * 32 + ((((quad << 1))     ^ sw8_) << 2);           \
        const int o1 = n * 32 + ((((quad << 1) | 1) ^ sw8_) << 2);           \
        float pf[8], gf[8];                                                  \
        *(float4*)&pf[0] = *(const float4*)&Sst[b][0][o0];                   \
        *(float4*)&pf[4] = *(const float4*)&Sst[b][0][o1];                   \
        *(float4*)&gf[0] = *(const float4*)&Sst[b][1][o0];                   \
        *(float4*)&gf[4] = *(const float4*)&Sst[b][1][o1];                   \
        COMPT(t, pf, gf)                                                     \
    }

// V window: lower 16 k-rows from ring slot SLO, upper from slot SHI
#define VPASS(SLO, SHI)                                                      \
    {                                                                        \
        const int koff = ((quad < 2) ? (SLO) : (SHI)) * 16 + (quad & 1) * 8; \
        const int rb   = n * CS + koff;                                      \
        const short8 bp  = ht_load(&ht[0 * CH_STRIDE + rb]);                 \
        const short8 bg  = ht_load(&ht[1 * CH_STRIDE + rb]);                 \
        const short8 bpp = ht_load(&ht[2 * CH_STRIDE + rb]);                 \
        const short8 bgg = ht_load(&ht[3 * CH_STRIDE + rb]);                 \
        const short8 bpg = ht_load(&ht[4 * CH_STRIDE + rb]);                 \
        const floatx4 z = {0.f, 0.f, 0.f, 0.f};                              \
        const floatx4 mp  = __builtin_amdgcn_mfma_f32_16x16x32_bf16(band, bp,  z, 0, 0, 0); \
        const floatx4 mg  = __builtin_amdgcn_mfma_f32_16x16x32_bf16(band, bg,  z, 0, 0, 0); \
        const floatx4 mpp = __builtin_amdgcn_mfma_f32_16x16x32_bf16(band, bpp, z, 0, 0, 0); \
        const floatx4 mgg = __builtin_amdgcn_mfma_f32_16x16x32_bf16(band, bgg, z, 0, 0, 0); \
        const floatx4 mpg = __builtin_amdgcn_mfma_f32_16x16x32_bf16(band, bpg, z, 0, 0, 0); \
        _Pragma("unroll")                                                    \
        for (int r = 0; r < 4; ++r) {                                        \
            const float mu1 = mp[r], mu2 = mg[r];                            \
            const float mu1sq = mu1 * mu1, mu2sq = mu2 * mu2;                \
            const float mu12 = mu1 * mu2;                                    \
            const float s1  = mpp[r] - mu1sq;                                \
            const float s2  = mgg[r] - mu2sq;                                \
            const float s12 = mpg[r] - mu12;                                 \
            const float num = (2.f * mu12 + C1) * (2.f * s12 + C2);          \
            const float den = (mu1sq + mu2sq + C1) * (s1 + s2 + C2);         \
            lsum += num * __builtin_amdgcn_rcpf(den);                        \
        }                                                                    \
    }

// gfx9 s_waitcnt imm: vmcnt[3:0]=bits3:0, expcnt=bits6:4, lgkmcnt=bits11:8,
// vmcnt[5:4]=bits15:14. lgkm/exp = no-wait (15/7).
#define WAITV8 { __builtin_amdgcn_s_waitcnt(0x0F78); __builtin_amdgcn_sched_barrier(0); }
#define WAITV4 { __builtin_amdgcn_s_waitcnt(0x0F74); __builtin_amdgcn_sched_barrier(0); }
#define WAITV0 { __builtin_amdgcn_s_waitcnt(0x0F70); __builtin_amdgcn_sched_barrier(0); }
#define SBAR __builtin_amdgcn_sched_barrier(0);

    const float C1 = 1e-4f, C2 = 9e-4f;
    float lsum = 0.f;

    // ---- prologue: 3 tiles of DMA in flight ----
    STAGE(0, 0)
    STAGE(1, 1)
    STAGE(2, 2)

    // t = 0
    WAITV8 FIX(0, 0) COMPL(0, 0) SBAR STAGE(3, 0)
    // t = 1
    WAITV8 FIX(1, 1) COMPL(1, 1) SBAR STAGE(4, 1) VPASS(0, 1)

    // ---- steady state: t = 2..13 (fully unrolled; b = t%3 static) ----
#pragma unroll
    for (int t = 2; t <= 13; ++t) {
        const int b = t % 3;
        WAITV8
        FIX(t, b)
        COMPL(t, b)
        SBAR
        STAGE(t + 3, b)
        VPASS((t - 1) & 1, t & 1)
    }

    // ---- drain: tiles 14,15,16 (buffers 2,0,1) ----
    WAITV8 FIX(14, 2) COMPL(14, 2) VPASS(1, 0)   // window 13
    WAITV4 FIX(15, 0) COMPL(15, 0) VPASS(0, 1)   // window 14
    WAITV0 FIX(16, 1) COMPL(16, 1) VPASS(1, 0)   // window 15

    // ---- wave reduction -> one partial per block ----
#pragma unroll
    for (int off = 32; off > 0; off >>= 1)
        lsum += __shfl_down(lsum, off);
    if (lane == 0)
        partials[(plane * 2 + yh) * 32 + bx] = lsum;
}

__global__ __launch_bounds__(1024) void ssim_finalize(
        const float* __restrict__ partials, float* __restrict__ out,
        int nparts, double inv_n)
{
    __shared__ double ws[16];
    double s = 0.0;
    for (int i = threadIdx.x; i < nparts; i += 1024)
        s += (double)partials[i];
#pragma unroll
    for (int off = 32; off > 0; off >>= 1)
        s += __shfl_down(s, off);
    if ((threadIdx.x & 63) == 0) ws[threadIdx.x >> 6] = s;
    __syncthreads();
    if (threadIdx.x == 0) {
        double t = 0.0;
#pragma unroll
        for (int i = 0; i < 16; ++i) t += ws[i];
        out[0] = (float)(1.0 - t * inv_n);
    }
}

extern "C" void kernel_launch(void* const* d_in, const int* in_sizes, int n_in,
                              void* d_out, int out_size, void* d_ws, size_t ws_size,
                              hipStream_t stream)
{
    const float* pred = (const float*)d_in[0];
    const float* gt   = (const float*)d_in[1];
    float* out        = (float*)d_out;
    float* partials   = (float*)d_ws;          // 32*2*48 = 3072 floats

    const long n = (long)in_sizes[0];
    const int planes = (int)(n / (long)(IMG * IMG));   // B*C = 48

    dim3 grid(32, 2, planes);                  // 16-col x 256-row wave strips
    ssim_mfma_dma<<<grid, 64, 0, stream>>>(pred, gt, partials);
    ssim_finalize<<<1, 1024, 0, stream>>>(partials, out,
                                          32 * 2 * planes, 1.0 / (double)n);
}